// Round 1
// baseline (416.470 us; speedup 1.0000x reference)
//
#include <hip/hip_runtime.h>

#define B_SZ 2048
#define T_SZ 2048

using f32x16 = float __attribute__((ext_vector_type(16)));

// DPP move: result[lane] = src[perm(lane)] (quad_perm / row_ror patterns)
template<int CTRL>
__device__ __forceinline__ float dppf(float v) {
  int r = __builtin_amdgcn_update_dpp(0, __builtin_bit_cast(int, v), CTRL, 0xf, 0xf, true);
  return __builtin_bit_cast(float, r);
}

// lane ^ 16 within each 32-half (BitMode: and=0x1F, or=0, xor=0x10)
__device__ __forceinline__ float swz16(float v) {
  return __builtin_bit_cast(float,
      __builtin_amdgcn_ds_swizzle(__builtin_bit_cast(int, v), 0x401F));
}

__device__ __forceinline__ float bperm(int addr_bytes, float v) {
  return __builtin_bit_cast(float,
      __builtin_amdgcn_ds_bpermute(addr_bytes, __builtin_bit_cast(int, v)));
}

__global__ __launch_bounds__(256, 2) void sss_kernel(
    const float* __restrict__ x0p, const float* __restrict__ up,
    const float* __restrict__ tfp, const float* __restrict__ thp,
    const float* __restrict__ tup, const float* __restrict__ typ,
    const float* __restrict__ W1p, const float* __restrict__ b1p,
    const float* __restrict__ W2p, const float* __restrict__ Whp,
    float* __restrict__ outp)
{
  const int lane = threadIdx.x & 63;
  const int wv   = __builtin_amdgcn_readfirstlane((int)(threadIdx.x >> 6));
  const int b    = blockIdx.x * 4 + wv;   // one wave per batch row

  // ---- prologue: per-lane weights (lane = hidden unit) ----
  const float w1x0 = W1p[0 * 64 + lane];
  const float w1x1 = W1p[1 * 64 + lane];
  const float w1x2 = W1p[2 * 64 + lane];
  const float w1x3 = W1p[3 * 64 + lane];
  const float w1u0 = W1p[4 * 64 + lane];
  const float w1u1 = W1p[5 * 64 + lane];

  // c = b1 + theta_f-part of feat@W1 (loop-invariant)
  float cc = b1p[lane];
#pragma unroll
  for (int j = 0; j < 5; ++j)
    cc = fmaf(tfp[j], W1p[(6 + j) * 64 + lane], cc);

  const float scale = tup[0] / typ[0];
  const float4 w2r = ((const float4*)W2p)[lane];   // W2[lane][0..3]
  const float w2_0 = w2r.x * scale;
  const float w2_1 = w2r.y * scale;
  const float w2_2 = w2r.z * scale;
  const float w2_3 = w2r.w * scale;
  // hoisted L1 fold selects (select commutes with the common factor h)
  const bool lb0 = lane & 1;
  const bool lb1 = (lane >> 1) & 1;
  const float w2A = lb0 ? w2_1 : w2_0;
  const float w2B = lb0 ? w2_0 : w2_1;
  const float w2C = lb0 ? w2_3 : w2_2;
  const float w2D = lb0 ? w2_2 : w2_3;

  const float wh0 = Whp[0], wh1 = Whp[1], wh2 = Whp[2], wh3 = Whp[3];
  const float th  = thp[0];

  // state (replicated across lanes)
  float x0v = x0p[b * 4 + 0];
  float x1v = x0p[b * 4 + 1];
  float x2v = x0p[b * 4 + 2];
  float x3v = x0p[b * 4 + 3];
  // y0 = h(x_0), UNCLAMPED (matches reference)
  float yv = fmaf(x3v, wh3, fmaf(x2v, wh2, fmaf(x1v, wh1, fmaf(x0v, wh0, th))));

  const f32x16* up16 = (const f32x16*)(up + (size_t)b * (T_SZ * 2)); // 8 steps/chunk
  float* outx = outp + (size_t)b * (T_SZ * 4);
  float* outy = outp + (size_t)B_SZ * T_SZ * 4 + (size_t)b * T_SZ;

  const int addr32 = (lane ^ 32) << 2;
  const int addr48 = (lane ^ 48) << 2;

  f32x16 uch = up16[0];
  const int gmax = T_SZ / 8 - 1;

  for (int blk = 0; blk < T_SZ; blk += 64) {
    float bx0 = 0.f, bx1 = 0.f, bx2 = 0.f, bx3 = 0.f, byv = 0.f;
#pragma unroll 2
    for (int seg = 0; seg < 8; ++seg) {
      int g = (blk >> 3) + seg + 1;          // prefetch next 8-step u chunk
      g = g > gmax ? gmax : g;
      const f32x16 unx = up16[g];
      const int wbase = seg * 8;
#pragma unroll
      for (int j = 0; j < 8; ++j) {
        // capture PRE-update carry into the 64-step output window
        const bool m = (lane == wbase + j);
        bx0 = m ? x0v : bx0;
        bx1 = m ? x1v : bx1;
        bx2 = m ? x2v : bx2;
        bx3 = m ? x3v : bx3;
        byv = m ? yv  : byv;

        const float u0 = uch[2 * j];
        const float u1 = uch[2 * j + 1];

        // hidden pre-activation for unit = lane
        float acc = fmaf(u0, w1u0, cc);
        acc = fmaf(u1, w1u1, acc);
        acc = fmaf(x0v, w1x0, acc);
        acc = fmaf(x1v, w1x1, acc);
        acc = fmaf(x2v, w1x2, acc);
        acc = fmaf(x3v, w1x3, acc);

        // tanh(a) = 1 - 2/(exp(2a)+1), saturates correctly at +-inf
        const float e  = __builtin_amdgcn_exp2f(acc * 2.8853900817779268f);
        const float rr = __builtin_amdgcn_rcpf(e + 1.0f);
        const float h  = fmaf(-2.0f, rr, 1.0f);

        // 64->4 reduction: dx_k = sum_l h_l*W2s[l][k]; end: lane holds dx[lane&3]
        const float pA = h * w2A, pB = h * w2B, pC = h * w2C, pD = h * w2D;
        const float r0 = pA + dppf<0xB1>(pB);     // xor1 (quad_perm [1,0,3,2])
        const float r1 = pC + dppf<0xB1>(pD);
        const float keep = lb1 ? r1 : r0;
        const float send = lb1 ? r0 : r1;
        float v = keep + dppf<0x4E>(send);        // xor2 (quad_perm [2,3,0,1])
        v += dppf<0x124>(v);                      // row_ror:4
        v += dppf<0x128>(v);                      // row_ror:8  -> 16-group sums
        const float a16 = swz16(v);               // ^16 (DS, independent)
        const float a32 = bperm(addr32, v);       // ^32
        const float a48 = bperm(addr48, v);       // ^48
        v = (v + a16) + (a32 + a48);              // full 64-lane sum, k = lane&3

        // broadcast the 4 sums to all lanes (quad contains all k)
        const float dx0 = dppf<0x00>(v);
        const float dx1 = dppf<0x55>(v);
        const float dx2 = dppf<0xAA>(v);
        const float dx3 = dppf<0xFF>(v);

        const float xr0 = x0v + dx0;
        const float xr1 = x1v + dx1;
        const float xr2 = x2v + dx2;
        const float xr3 = x3v + dx3;

        // y from PRE-clip state
        float t0 = fmaf(xr1, wh1, fmaf(xr0, wh0, th));
        float t1 = fmaf(xr3, wh3, xr2 * wh2);
        yv = __builtin_amdgcn_fmed3f(t0 + t1, 0.0f, 10.0f);

        // clip x (component 3 unbounded)
        x0v = __builtin_amdgcn_fmed3f(xr0, 0.0f, 10.0f);
        x1v = __builtin_amdgcn_fmed3f(xr1, 0.0f, 10.0f);
        x2v = __builtin_amdgcn_fmed3f(xr2, 0.0f, 10.0f);
        x3v = xr3;
      }
      uch = unx;
    }
    // flush 64-step window: fully coalesced
    float4 bx;
    bx.x = bx0; bx.y = bx1; bx.z = bx2; bx.w = bx3;
    *(float4*)(outx + (size_t)(blk + lane) * 4) = bx;
    outy[blk + lane] = byv;
  }
}

extern "C" void kernel_launch(void* const* d_in, const int* in_sizes, int n_in,
                              void* d_out, int out_size, void* d_ws, size_t ws_size,
                              hipStream_t stream) {
  (void)in_sizes; (void)n_in; (void)out_size; (void)d_ws; (void)ws_size;
  sss_kernel<<<dim3(B_SZ / 4), dim3(256), 0, stream>>>(
      (const float*)d_in[0], (const float*)d_in[1], (const float*)d_in[2],
      (const float*)d_in[3], (const float*)d_in[4], (const float*)d_in[5],
      (const float*)d_in[6], (const float*)d_in[7], (const float*)d_in[8],
      (const float*)d_in[9], (float*)d_out);
}

// Round 4
// 389.488 us; speedup vs baseline: 1.0693x; 1.0693x over previous
//
#include <hip/hip_runtime.h>

#define B_SZ 2048
#define T_SZ 2048

using f32x16 = float __attribute__((ext_vector_type(16)));

// DPP move: result[lane] = src[perm(lane)] (quad_perm / row_ror patterns)
template<int CTRL>
__device__ __forceinline__ float dppf(float v) {
  int r = __builtin_amdgcn_update_dpp(0, __builtin_bit_cast(int, v), CTRL, 0xf, 0xf, true);
  return __builtin_bit_cast(float, r);
}

// lane ^ 16 within each 32-half (BitMode: and=0x1F, or=0, xor=0x10)
__device__ __forceinline__ float swz16(float v) {
  return __builtin_bit_cast(float,
      __builtin_amdgcn_ds_swizzle(__builtin_bit_cast(int, v), 0x401F));
}

__device__ __forceinline__ float bperm(int addr_bytes, float v) {
  return __builtin_bit_cast(float,
      __builtin_amdgcn_ds_bpermute(addr_bytes, __builtin_bit_cast(int, v)));
}

__global__ __launch_bounds__(256, 2) void sss_kernel(
    const float* __restrict__ x0p, const float* __restrict__ up,
    const float* __restrict__ tfp, const float* __restrict__ thp,
    const float* __restrict__ tup, const float* __restrict__ typ,
    const float* __restrict__ W1p, const float* __restrict__ b1p,
    const float* __restrict__ W2p, const float* __restrict__ Whp,
    float* __restrict__ outp)
{
  const int lane = threadIdx.x & 63;
  const int wv   = __builtin_amdgcn_readfirstlane((int)(threadIdx.x >> 6));
  const int b    = blockIdx.x * 4 + wv;   // one wave per batch row

  // ---- prologue: per-lane weights (lane = hidden unit) ----
  // fold K = 2*log2(e) into W1/cc so tanh needs no pre-multiply:
  // tanh(a) = 1 - 2/(exp2(K*a)+1)
  const float K = 2.8853900817779268f;
  const float w1x0 = W1p[0 * 64 + lane] * K;
  const float w1x1 = W1p[1 * 64 + lane] * K;
  const float w1x2 = W1p[2 * 64 + lane] * K;
  const float w1x3 = W1p[3 * 64 + lane] * K;
  const float w1u0 = W1p[4 * 64 + lane] * K;
  const float w1u1 = W1p[5 * 64 + lane] * K;

  float cc = b1p[lane];
#pragma unroll
  for (int j = 0; j < 5; ++j)
    cc = fmaf(tfp[j], W1p[(6 + j) * 64 + lane], cc);
  cc *= K;

  const float scale = tup[0] / typ[0];
  const float4 w2r = ((const float4*)W2p)[lane];   // W2[lane][0..3]
  const float w2_0 = w2r.x * scale;
  const float w2_1 = w2r.y * scale;
  const float w2_2 = w2r.z * scale;
  const float w2_3 = w2r.w * scale;
  // hoisted L1 fold selects (select commutes with the common factor h)
  const bool lb0 = lane & 1;
  const bool lb1 = (lane >> 1) & 1;
  const float w2A = lb0 ? w2_1 : w2_0;
  const float w2B = lb0 ? w2_0 : w2_1;
  const float w2C = lb0 ? w2_3 : w2_2;
  const float w2D = lb0 ? w2_2 : w2_3;

  const float whl = Whp[lane & 3];     // Wh[k][0], k = lane&3
  const float th  = thp[0];

  // per-lane clip bounds: components 0..2 -> [0,10], component 3 unbounded
  const float lo = ((lane & 3) == 3) ? -__builtin_inff() : 0.0f;
  const float hi = ((lane & 3) == 3) ?  __builtin_inff() : 10.0f;

  // per-lane state: xlane = x[lane&3] (replicated per quad)
  float xlane = x0p[b * 4 + (lane & 3)];
  float x0v = dppf<0x00>(xlane);
  float x1v = dppf<0x55>(xlane);
  float x2v = dppf<0xAA>(xlane);
  float x3v = dppf<0xFF>(xlane);

  // y0 = h(x_0), UNCLAMPED (matches reference)
  float p0 = xlane * whl;
  p0 += dppf<0xB1>(p0);
  p0 += dppf<0x4E>(p0);
  float yv = p0 + th;

  // ---- per-step direct output store setup ----
  // lanes 0-3: outx[b][t][lane]; lane 4: outy[b][t]; lanes 5-63 masked off
  unsigned voff, vinc;
  if (lane < 4) {
    voff = (unsigned)(b * (T_SZ * 4) + lane) * 4u;
    vinc = 16u;
  } else {
    voff = (unsigned)((unsigned)B_SZ * T_SZ * 4u + (unsigned)b * T_SZ) * 4u;
    vinc = (lane == 4) ? 4u : 0u;
  }
  const bool doSt = (lane < 5);
  const bool is4  = (lane == 4);

  const int addr32 = (lane ^ 32) << 2;
  const int addr48 = (lane ^ 48) << 2;

  const f32x16* up16 = (const f32x16*)(up + (size_t)b * (T_SZ * 2)); // 8 steps/chunk
  char* outB = (char*)outp;

  f32x16 uch = up16[0];
  const int NC = T_SZ / 8;

  for (int c = 0; c < NC; ++c) {
    const int g = (c + 1 < NC) ? c + 1 : NC - 1;   // prefetch next chunk
    const f32x16 unx = up16[g];
#pragma unroll
    for (int j = 0; j < 8; ++j) {
      // ---- emit PRE-update carry (x_step, y_step) ----
      const float vdata = is4 ? yv : xlane;
      if (doSt) *(float*)(outB + voff) = vdata;
      voff += vinc;

      const float u0 = uch[2 * j];
      const float u1 = uch[2 * j + 1];

      // hidden pre-activation (already scaled by K), two independent chains
      float a0 = fmaf(u0, w1u0, cc);
      a0 = fmaf(x0v, w1x0, a0);
      a0 = fmaf(x2v, w1x2, a0);
      float a1 = u1 * w1u1;
      a1 = fmaf(x1v, w1x1, a1);
      a1 = fmaf(x3v, w1x3, a1);
      const float acc = a0 + a1;

      // tanh(a) = 1 - 2/(exp2(acc)+1), saturates correctly at +-inf
      const float e  = __builtin_amdgcn_exp2f(acc);
      const float rr = __builtin_amdgcn_rcpf(e + 1.0f);
      const float h  = fmaf(-2.0f, rr, 1.0f);

      // 64->4 reduction: dx_k = sum_l h_l*W2s[l][k]; lane ends with dx[lane&3]
      const float pA = h * w2A, pB = h * w2B, pC = h * w2C, pD = h * w2D;
      const float r0 = pA + dppf<0xB1>(pB);     // xor1 (quad_perm [1,0,3,2])
      const float r1 = pC + dppf<0xB1>(pD);
      const float keep = lb1 ? r1 : r0;
      const float send = lb1 ? r0 : r1;
      float v = keep + dppf<0x4E>(send);        // xor2 (quad_perm [2,3,0,1])
      v += dppf<0x124>(v);                      // row_ror:4
      v += dppf<0x128>(v);                      // row_ror:8 -> 16-group sums
      // Round-1-proven tail: three parallel DS cross-lane ops, one wait
      const float a16 = swz16(v);               // ^16
      const float a32 = bperm(addr32, v);       // ^32
      const float a48 = bperm(addr48, v);       // ^48
      v = (v + a16) + (a32 + a48);              // full 64-lane sum, k = lane&3

      // per-lane state update: w = pre-clip x_raw[lane&3]
      const float w = xlane + v;
      xlane = __builtin_amdgcn_fmed3f(w, lo, hi);   // clip (comp 3: +-inf passes w)

      // y from PRE-clip state: quad reduce of w*wh
      float p = w * whl;
      p += dppf<0xB1>(p);
      p += dppf<0x4E>(p);
      yv = __builtin_amdgcn_fmed3f(p + th, 0.0f, 10.0f);

      // broadcast clipped state for next step's matvec
      x0v = dppf<0x00>(xlane);
      x1v = dppf<0x55>(xlane);
      x2v = dppf<0xAA>(xlane);
      x3v = dppf<0xFF>(xlane);
    }
    uch = unx;
  }
}

extern "C" void kernel_launch(void* const* d_in, const int* in_sizes, int n_in,
                              void* d_out, int out_size, void* d_ws, size_t ws_size,
                              hipStream_t stream) {
  (void)in_sizes; (void)n_in; (void)out_size; (void)d_ws; (void)ws_size;
  sss_kernel<<<dim3(B_SZ / 4), dim3(256), 0, stream>>>(
      (const float*)d_in[0], (const float*)d_in[1], (const float*)d_in[2],
      (const float*)d_in[3], (const float*)d_in[4], (const float*)d_in[5],
      (const float*)d_in[6], (const float*)d_in[7], (const float*)d_in[8],
      (const float*)d_in[9], (float*)d_out);
}

// Round 5
// 370.138 us; speedup vs baseline: 1.1252x; 1.0523x over previous
//
#include <hip/hip_runtime.h>

#define B_SZ 2048
#define T_SZ 2048

using f32x16 = float __attribute__((ext_vector_type(16)));

// DPP move: result[lane] = src[perm(lane)] (quad_perm / row_ror patterns)
template<int CTRL>
__device__ __forceinline__ float dppf(float v) {
  int r = __builtin_amdgcn_update_dpp(0, __builtin_bit_cast(int, v), CTRL, 0xf, 0xf, true);
  return __builtin_bit_cast(float, r);
}

// lane ^ 16 within each 32-half (BitMode: and=0x1F, or=0, xor=0x10) - proven R1/R4
__device__ __forceinline__ float swz16(float v) {
  return __builtin_bit_cast(float,
      __builtin_amdgcn_ds_swizzle(__builtin_bit_cast(int, v), 0x401F));
}

// 2 batch rows per wave: lanes 0-31 = row A, lanes 32-63 = row B.
// Each lane owns hidden units j=lane&31 and j+32.
__global__ __launch_bounds__(256) void sss_kernel(
    const float* __restrict__ x0p, const float* __restrict__ up,
    const float* __restrict__ tfp, const float* __restrict__ thp,
    const float* __restrict__ tup, const float* __restrict__ typ,
    const float* __restrict__ W1p, const float* __restrict__ b1p,
    const float* __restrict__ W2p, const float* __restrict__ Whp,
    float* __restrict__ outp)
{
  const int lane = threadIdx.x & 63;
  const int wv   = __builtin_amdgcn_readfirstlane((int)(threadIdx.x >> 6));
  const int half = lane >> 5;                    // 0: row A, 1: row B
  const int j    = lane & 31;                    // unit pair (j, j+32)
  const int b    = blockIdx.x * 8 + wv * 2 + half;   // per-LANE batch row

  // ---- prologue: per-lane weights for both units ----
  // fold K = 2*log2(e) into W1/cc: tanh(a) = 1 - 2/(exp2(K*a)+1)
  const float K = 2.8853900817779268f;
  float w1a[6], w1b[6];
#pragma unroll
  for (int c = 0; c < 6; ++c) {
    w1a[c] = W1p[c * 64 + j]      * K;
    w1b[c] = W1p[c * 64 + j + 32] * K;
  }
  float cca = b1p[j], ccb = b1p[j + 32];
#pragma unroll
  for (int q = 0; q < 5; ++q) {
    cca = fmaf(tfp[q], W1p[(6 + q) * 64 + j],      cca);
    ccb = fmaf(tfp[q], W1p[(6 + q) * 64 + j + 32], ccb);
  }
  cca *= K; ccb *= K;

  const float scale = tup[0] / typ[0];
  const float4 wra = ((const float4*)W2p)[j];
  const float4 wrb = ((const float4*)W2p)[j + 32];
  const float sa0 = wra.x * scale, sa1 = wra.y * scale, sa2 = wra.z * scale, sa3 = wra.w * scale;
  const float sb0 = wrb.x * scale, sb1 = wrb.y * scale, sb2 = wrb.z * scale, sb3 = wrb.w * scale;
  // hoisted L1 fold selects (select commutes with the common factor h)
  const bool lb0 = lane & 1;
  const bool lb1 = (lane >> 1) & 1;
  const float w2Aa = lb0 ? sa1 : sa0;
  const float w2Ba = lb0 ? sa0 : sa1;
  const float w2Ca = lb0 ? sa3 : sa2;
  const float w2Da = lb0 ? sa2 : sa3;
  const float w2Ab = lb0 ? sb1 : sb0;
  const float w2Bb = lb0 ? sb0 : sb1;
  const float w2Cb = lb0 ? sb3 : sb2;
  const float w2Db = lb0 ? sb2 : sb3;

  const float whl = Whp[lane & 3];     // Wh[k][0], k = lane&3
  const float th  = thp[0];

  // per-lane clip bounds: components 0..2 -> [0,10], component 3 unbounded
  const float lo = ((lane & 3) == 3) ? -__builtin_inff() : 0.0f;
  const float hi = ((lane & 3) == 3) ?  __builtin_inff() : 10.0f;

  // per-lane state: xlane = x[lane&3] of THIS lane's row (replicated per quad)
  float xlane = x0p[b * 4 + (lane & 3)];
  float x0v = dppf<0x00>(xlane);
  float x1v = dppf<0x55>(xlane);
  float x2v = dppf<0xAA>(xlane);
  float x3v = dppf<0xFF>(xlane);

  // y0 = h(x_0), UNCLAMPED (matches reference)
  float p0 = xlane * whl;
  p0 += dppf<0xB1>(p0);
  p0 += dppf<0x4E>(p0);
  float yv = p0 + th;

  // ---- per-step direct output store setup ----
  // per half: sub-lanes 0-3 -> outx[b][t][k]; sub-lane 4 -> outy[b][t]
  const int sl = lane & 31;
  unsigned voff, vinc;
  if (sl < 4) {
    voff = (unsigned)(b * (T_SZ * 4) + sl) * 4u;
    vinc = 16u;
  } else {
    voff = (unsigned)((unsigned)B_SZ * T_SZ * 4u + (unsigned)b * T_SZ) * 4u;
    vinc = (sl == 4) ? 4u : 0u;
  }
  const bool doSt = (sl < 5);
  const bool is4  = (sl == 4);

  // per-lane u chunk base (32 lanes of a half share one address -> broadcast)
  const f32x16* up16 = (const f32x16*)(up + (size_t)b * (T_SZ * 2)); // 8 steps/chunk
  char* outB = (char*)outp;

  f32x16 uch = up16[0];
  const int NC = T_SZ / 8;

  for (int c = 0; c < NC; ++c) {
    const int g = (c + 1 < NC) ? c + 1 : NC - 1;   // prefetch next chunk
    const f32x16 unx = up16[g];
#pragma unroll
    for (int jj = 0; jj < 8; ++jj) {
      // ---- emit PRE-update carry (x_step, y_step) for both rows ----
      const float vdata = is4 ? yv : xlane;
      if (doSt) *(float*)(outB + voff) = vdata;
      voff += vinc;

      const float u0 = uch[2 * jj];
      const float u1 = uch[2 * jj + 1];

      // hidden pre-activation for units j and j+32 (scaled by K), 4 chains
      float a0 = fmaf(u0, w1a[4], cca);
      a0 = fmaf(x0v, w1a[0], a0);
      a0 = fmaf(x2v, w1a[2], a0);
      float a1 = u1 * w1a[5];
      a1 = fmaf(x1v, w1a[1], a1);
      a1 = fmaf(x3v, w1a[3], a1);
      const float acca = a0 + a1;

      float b0 = fmaf(u0, w1b[4], ccb);
      b0 = fmaf(x0v, w1b[0], b0);
      b0 = fmaf(x2v, w1b[2], b0);
      float b1 = u1 * w1b[5];
      b1 = fmaf(x1v, w1b[1], b1);
      b1 = fmaf(x3v, w1b[3], b1);
      const float accb = b0 + b1;

      // tanh(a) = 1 - 2/(exp2(acc)+1)
      const float ea = __builtin_amdgcn_exp2f(acca);
      const float ra = __builtin_amdgcn_rcpf(ea + 1.0f);
      const float ha = fmaf(-2.0f, ra, 1.0f);
      const float eb = __builtin_amdgcn_exp2f(accb);
      const float rb = __builtin_amdgcn_rcpf(eb + 1.0f);
      const float hb = fmaf(-2.0f, rb, 1.0f);

      // per-lane unit-pair fold, then 32-lane tree (quad channels k=lane&3)
      const float qA = fmaf(hb, w2Ab, ha * w2Aa);
      const float qB = fmaf(hb, w2Bb, ha * w2Ba);
      const float qC = fmaf(hb, w2Cb, ha * w2Ca);
      const float qD = fmaf(hb, w2Db, ha * w2Da);
      const float r0 = qA + dppf<0xB1>(qB);     // xor1 (quad_perm [1,0,3,2])
      const float r1 = qC + dppf<0xB1>(qD);
      const float keep = lb1 ? r1 : r0;
      const float send = lb1 ? r0 : r1;
      float v = keep + dppf<0x4E>(send);        // xor2 (quad_perm [2,3,0,1])
      v += dppf<0x124>(v);                      // row_ror:4
      v += dppf<0x128>(v);                      // row_ror:8 -> 16-row sums
      v += swz16(v);                            // ^16 within half -> full row sum

      // per-lane state update: w = pre-clip x_raw[lane&3]
      const float w = xlane + v;
      xlane = __builtin_amdgcn_fmed3f(w, lo, hi);   // clip (comp 3 unbounded)

      // y from PRE-clip state: quad reduce of w*wh
      float p = w * whl;
      p += dppf<0xB1>(p);
      p += dppf<0x4E>(p);
      yv = __builtin_amdgcn_fmed3f(p + th, 0.0f, 10.0f);

      // broadcast clipped state for next step's matvec (within quad = within row)
      x0v = dppf<0x00>(xlane);
      x1v = dppf<0x55>(xlane);
      x2v = dppf<0xAA>(xlane);
      x3v = dppf<0xFF>(xlane);
    }
    uch = unx;
  }
}

extern "C" void kernel_launch(void* const* d_in, const int* in_sizes, int n_in,
                              void* d_out, int out_size, void* d_ws, size_t ws_size,
                              hipStream_t stream) {
  (void)in_sizes; (void)n_in; (void)out_size; (void)d_ws; (void)ws_size;
  sss_kernel<<<dim3(B_SZ / 8), dim3(256), 0, stream>>>(
      (const float*)d_in[0], (const float*)d_in[1], (const float*)d_in[2],
      (const float*)d_in[3], (const float*)d_in[4], (const float*)d_in[5],
      (const float*)d_in[6], (const float*)d_in[7], (const float*)d_in[8],
      (const float*)d_in[9], (float*)d_out);
}